// Round 16
// baseline (159.004 us; speedup 1.0000x reference)
//
#include <hip/hip_runtime.h>
#include <math.h>

#define BB 128
#define LL 720
#define CC 321
#define HH 128
#define PP 336
#define MM 512
#define NSTEP 23   // K-steps of 32 (736 = 23*32, zero-padded past 720)

typedef __attribute__((ext_vector_type(8))) short bf16x8;
typedef __attribute__((ext_vector_type(4))) float f32x4;

__device__ __forceinline__ short f2bf(float x) {
  unsigned u = __builtin_bit_cast(unsigned, x);
  u = (u + 0x7FFFu + ((u >> 16) & 1u)) >> 16;
  return (short)u;
}

// packed position of k-within-32-group: fragment lg*8 + half*4 + j
__device__ __forceinline__ int packpos(int kw) {
  return ((kw & 15) >> 2) * 8 + (kw >> 4) * 4 + (kw & 3);
}

// async global->LDS, 16 bytes per lane; lds ptr must be wave-uniform base
__device__ __forceinline__ void gload_lds16(const short* g, short* l) {
  __builtin_amdgcn_global_load_lds(
      (const __attribute__((address_space(1))) unsigned int*)g,
      (__attribute__((address_space(3))) unsigned int*)l, 16, 0, 0);
}

// ---------------------------------------------------------------------------
// Kernel 1 (v5): smeared weights -> W image for gemm1 (BK=32). Unchanged:
//   wimg[s][h] = 64-short row of 8 16B slots; slot (br*4+lg)^(h&7) holds the
//   packed fragment of Weff_br[h][s*32 + ...]. 23 x 16 KB = 368 KB.
// ---------------------------------------------------------------------------
__global__ void weff_kernel(const float* __restrict__ Ws1,
                            const float* __restrict__ Wt1,
                            short* __restrict__ wimg) {
  int idx = blockIdx.x * 256 + threadIdx.x;
  if (idx >= HH * NSTEP * 32) return;
  int j = idx % (NSTEP * 32), h = idx / (NSTEP * 32);
  int s = j >> 5, kw = j & 31;
  int half = kw >> 4, lg = (kw >> 2) & 3, jj = kw & 3;
  size_t base = ((size_t)(s * 128 + h)) * 64 + half * 4 + jj;
  int slotS = (0 + lg) ^ (h & 7);
  int slotT = (4 + lg) ^ (h & 7);
  if (j >= LL) {
    wimg[base + slotS * 8] = 0;
    wimg[base + slotT * 8] = 0;
    return;
  }
  float ss = 0.f, st = 0.f;
  if (j == 0) {
    for (int l = 0; l <= 12; ++l) {
      float w = 13.f - (float)l;
      ss += w * Ws1[h * LL + l];
      st += w * Wt1[h * LL + l];
    }
  } else if (j == LL - 1) {
    for (int d = 0; d <= 12; ++d) {
      float w = 13.f - (float)d;
      ss += w * Ws1[h * LL + LL - 1 - d];
      st += w * Wt1[h * LL + LL - 1 - d];
    }
  } else {
    int lo = j - 12 < 0 ? 0 : j - 12;
    int hi = j + 12 > LL - 1 ? LL - 1 : j + 12;
    for (int l = lo; l <= hi; ++l) {
      ss += Ws1[h * LL + l];
      st += Wt1[h * LL + l];
    }
  }
  ss *= (1.f / 25.f);
  st *= (1.f / 25.f);
  wimg[base + slotS * 8] = f2bf(Ws1[h * LL + j] - ss);
  wimg[base + slotT * 8] = f2bf(st);
}

// ---------------------------------------------------------------------------
// Kernel 1d (v3): x -> per-(block,step) staged bf16 images.
//   NEW layout: chunk(nl, lg) = lg*64 + (nl ^ (2*lg)).
//   Per lg-instruction the wave writes a DENSE contiguous 1 KB (the XOR only
//   permutes within 128B blocks) -> fully coalesced 64B sectors, fixing the
//   r14/r15 4x write amplification (16B scatters). gemm1 ds_read matches;
//   bank quadruple = (lr%8)^(2lg) -> disjoint across lg groups, 2-way free.
// ---------------------------------------------------------------------------
__global__ void xstage_kernel(const float* __restrict__ x,
                              short* __restrict__ ximg) {
  int blk = blockIdx.x, s = blockIdx.y;
  int t = threadIdx.x;  // n-local 0..63
  int n = blk * 64 + t;
  int b = n / CC, c = n - b * CC;
  const float* xp = x + (size_t)b * (LL * CC) + c;
  float v[32];
  int k0 = s * 32;
#pragma unroll
  for (int kk = 0; kk < 32; ++kk) {
    int k = k0 + kk;
    v[kk] = (k < LL) ? xp[(size_t)k * CC] : 0.f;
  }
  __builtin_amdgcn_sched_barrier(0);  // keep the 32 loads batched
  short* dst = ximg + ((size_t)(blk * NSTEP + s)) * 2048;
#pragma unroll
  for (int lg = 0; lg < 4; ++lg) {
    int chunk = lg * 64 + (t ^ (2 * lg));
    union { short sv[8]; int4 q; } u;
#pragma unroll
    for (int j = 0; j < 4; ++j) {
      u.sv[j] = f2bf(v[lg * 4 + j]);
      u.sv[j + 4] = f2bf(v[16 + lg * 4 + j]);
    }
    *(int4*)&dst[chunk * 8] = u.q;  // dense 1KB per wave-instruction
  }
}

// ---------------------------------------------------------------------------
// Kernel 1b: staged mem images for memenh (unchanged).
// ---------------------------------------------------------------------------
__global__ void memstage_kernel(const float* __restrict__ memS,
                                const float* __restrict__ memT,
                                short* __restrict__ stgS,
                                short* __restrict__ stgT) {
  int e = blockIdx.x * 256 + threadIdx.x;  // 0..32767
  int br = e >> 14;
  int s = e & 16383;
  const float* src = br ? memT : memS;
  short* dst = br ? stgT : stgS;
  int tt = s >> 11;                        // tile 0..7
  int c = s & 2047;
  int row = c >> 4, slot = c & 15;
  int sp = slot ^ (row & 7);
  int k = sp >> 2, lg = sp & 3;
  int ft = tt >> 1;
  short out[8];
  if ((tt & 1) == 0) {
    const float* r0 = src + (size_t)(ft * 128 + row) * 128 + k * 32 + lg * 4;
#pragma unroll
    for (int j = 0; j < 4; ++j) {
      out[j] = f2bf(r0[j]);
      out[j + 4] = f2bf(r0[16 + j]);
    }
  } else {
    int fbase = ft * 128 + k * 32 + lg * 4;
#pragma unroll
    for (int j = 0; j < 4; ++j) {
      out[j] = f2bf(src[(size_t)(fbase + j) * 128 + row]);
      out[j + 4] = f2bf(src[(size_t)(fbase + 16 + j) * 128 + row]);
    }
  }
  short4 a = make_short4(out[0], out[1], out[2], out[3]);
  short4 b = make_short4(out[4], out[5], out[6], out[7]);
  *(short4*)&dst[(size_t)s * 8] = a;
  *(short4*)&dst[(size_t)s * 8 + 4] = b;
}

// ---------------------------------------------------------------------------
// Kernel 1c: W2cat bf16 [336][512], fragment-packed per 32-group, + bias sum.
// ---------------------------------------------------------------------------
__global__ void w2cvt_kernel(const float* __restrict__ Ws2,
                             const float* __restrict__ Wt2,
                             const float* __restrict__ bs2,
                             const float* __restrict__ bt2,
                             short* __restrict__ W2b, float* __restrict__ b2) {
  int i = blockIdx.x * 256 + threadIdx.x;
  if (i < PP) b2[i] = bs2[i] + bt2[i];
  if (i >= PP * 512) return;
  int p = i >> 9, k = i & 511;
  float v = (k < 256) ? Ws2[p * 256 + k] : Wt2[p * 256 + (k - 256)];
  W2b[p * 512 + (k >> 5) * 32 + packpos(k & 31)] = f2bf(v);
}

// ---------------------------------------------------------------------------
// Kernel 2 (v11): MFMA dual-branch GEMM1 + sigmoid — pure gload_lds pipeline.
//   Identical to r15 except the x-fragment ds_read address matches the new
//   dense-write ximg layout: chunk = lg*64 + (nl ^ 2lg).
// ---------------------------------------------------------------------------
__global__ __launch_bounds__(256) void gemm1_mfma(
    const short* __restrict__ wimg, const short* __restrict__ ximg,
    const float* __restrict__ bs1, const float* __restrict__ bt1,
    short* __restrict__ r2s, short* __restrict__ r2t) {
  __shared__ __align__(16) short wbuf[2][8192];  // 2 x 16 KB
  __shared__ __align__(16) short xbuf[2][2048];  // 2 x 4 KB
  int tid = threadIdx.x;
  int w = tid >> 6, l = tid & 63, lr = l & 15, lg = l >> 4;
  int br = w >> 1, hb = (w & 1) * 64;
  int blk = blockIdx.x;
  int nb = blk * 64;  // 41088 = 642*64 exact

  const short* wsrc = wimg + (size_t)w * 2048 + l * 8;
  const short* xsrc = ximg + (size_t)blk * NSTEP * 2048 + tid * 8;

  f32x4 acc[4][4];  // [ht][ng]
#pragma unroll
  for (int i = 0; i < 4; ++i)
#pragma unroll
    for (int g = 0; g < 4; ++g) acc[i][g] = (f32x4){0.f, 0.f, 0.f, 0.f};

#define STAGE(ss, bb)                                                     \
  do {                                                                    \
    const short* ws_ = wsrc + (size_t)(ss)*8192;                          \
    _Pragma("unroll") for (int i = 0; i < 4; ++i)                         \
        gload_lds16(ws_ + i * 512, &wbuf[bb][w * 2048 + i * 512]);        \
    gload_lds16(xsrc + (size_t)(ss)*2048, &xbuf[bb][(tid & 192) * 8]);    \
  } while (0)

  STAGE(0, 0);
  __syncthreads();

  int cur = 0;
  for (int s = 0; s < NSTEP; ++s) {
    if (s < NSTEP - 1) STAGE(s + 1, cur ^ 1);

    const short* tw = &wbuf[cur][0];
    const short* tx = &xbuf[cur][0];
    bf16x8 afr[4], bfr[4];
#pragma unroll
    for (int ht = 0; ht < 4; ++ht) {
      int h = hb + ht * 16 + lr;
      int slot = (br * 4 + lg) ^ (h & 7);
      afr[ht] = *(const bf16x8*)&tw[h * 64 + slot * 8];
    }
#pragma unroll
    for (int ng = 0; ng < 4; ++ng) {
      int nl = ng * 16 + lr;
      int chunk = lg * 64 + (nl ^ (2 * lg));
      bfr[ng] = *(const bf16x8*)&tx[chunk * 8];
    }
#pragma unroll
    for (int ht = 0; ht < 4; ++ht)
#pragma unroll
      for (int ng = 0; ng < 4; ++ng)
        acc[ht][ng] = __builtin_amdgcn_mfma_f32_16x16x32_bf16(
            afr[ht], bfr[ng], acc[ht][ng], 0, 0, 0);

    __syncthreads();
    cur ^= 1;
  }
#undef STAGE

  // epilogue: sigmoid -> PACKED bf16 R at shorts [128..255] of each r2 row
  const float* bias = br ? bt1 : bs1;
  short* r2 = br ? r2t : r2s;
#pragma unroll
  for (int ht = 0; ht < 4; ++ht) {
    int h0 = hb + ht * 16 + lg * 4;
    int dst = (h0 >> 5) * 32 + lg * 8 + ((h0 >> 4) & 1) * 4;
    float4 bi4 = *(const float4*)&bias[h0];
    const float* pb = &bi4.x;
#pragma unroll
    for (int ng = 0; ng < 4; ++ng) {
      int n = nb + ng * 16 + lr;
      short4 v;
      short* pv = &v.x;
#pragma unroll
      for (int j = 0; j < 4; ++j)
        pv[j] = f2bf(1.f / (1.f + __expf(-(acc[ht][ng][j] + pb[j]))));
      *(short4*)&r2[(size_t)n * 256 + 128 + dst] = v;
    }
  }
}

// ---------------------------------------------------------------------------
// Kernel 3: pipelined MFMA memory-enhance (unchanged).
// ---------------------------------------------------------------------------
__global__ __launch_bounds__(256) void memenh_mfma(
    const short* __restrict__ stgS, const short* __restrict__ stgT,
    short* __restrict__ r2s, short* __restrict__ r2t) {
  int br = blockIdx.y;
  const short* stg = br ? stgT : stgS;
  short* r2 = br ? r2t : r2s;

  __shared__ __align__(16) short buf[2][16384];  // 64 KB
  int tid = threadIdx.x;
  int l = tid & 63, lr = l & 15, lg = l >> 4;
  int wbase = tid & 192;
  int n = blockIdx.x * 64 + (tid >> 6) * 16 + lr;

  bf16x8 brag[4];
  {
    const short* rb = r2 + (size_t)n * 256 + 128;
#pragma unroll
    for (int k = 0; k < 4; ++k)
      brag[k] = *(const bf16x8*)&rb[k * 32 + lg * 8];
  }

#define STAGE(t, bsel)                                                        \
  {                                                                           \
    const short* g = stg + (size_t)(t)*16384;                                 \
    _Pragma("unroll") for (int i = 0; i < 8; ++i) {                           \
      gload_lds16(g + (size_t)(i * 256 + tid) * 8,                            \
                  &buf[bsel][(i * 256 + wbase) * 8]);                         \
    }                                                                         \
  }

  STAGE(0, 0);
  __syncthreads();

  f32x4 accO[8];
#pragma unroll
  for (int i = 0; i < 8; ++i) accO[i] = (f32x4){0.f, 0.f, 0.f, 0.f};
  bf16x8 pb[4];
  float ssum = 0.f;
  int cur = 0;

#pragma unroll
  for (int t = 0; t < 8; ++t) {
    if (t < 7) STAGE(t + 1, cur ^ 1);
    const short* tb = &buf[cur][0];
    if ((t & 1) == 0) {
      f32x4 sc[8];
#pragma unroll
      for (int ft16 = 0; ft16 < 8; ++ft16) {
        f32x4 a = {0.f, 0.f, 0.f, 0.f};
#pragma unroll
        for (int k = 0; k < 4; ++k) {
          int row = ft16 * 16 + lr;
          int slot = (4 * k + lg) ^ (row & 7);
          bf16x8 af = *(const bf16x8*)&tb[row * 128 + slot * 8];
          a = __builtin_amdgcn_mfma_f32_16x16x32_bf16(af, brag[k], a, 0, 0, 0);
        }
        sc[ft16] = a;
      }
#pragma unroll
      for (int i = 0; i < 8; ++i) {
        f32x4 v = sc[i];
#pragma unroll
        for (int j = 0; j < 4; ++j) {
          float e = __expf(v[j]);
          v[j] = e;
          ssum += e;
        }
        sc[i] = v;
      }
#pragma unroll
      for (int t4 = 0; t4 < 4; ++t4) {
        f32x4 e0 = sc[2 * t4], e1 = sc[2 * t4 + 1];
        bf16x8 f;
        f[0] = f2bf(e0[0]); f[1] = f2bf(e0[1]);
        f[2] = f2bf(e0[2]); f[3] = f2bf(e0[3]);
        f[4] = f2bf(e1[0]); f[5] = f2bf(e1[1]);
        f[6] = f2bf(e1[2]); f[7] = f2bf(e1[3]);
        pb[t4] = f;
      }
    } else {
#pragma unroll
      for (int dt = 0; dt < 8; ++dt) {
#pragma unroll
        for (int k = 0; k < 4; ++k) {
          int row = dt * 16 + lr;
          int slot = (4 * k + lg) ^ (row & 7);
          bf16x8 af = *(const bf16x8*)&tb[row * 128 + slot * 8];
          accO[dt] =
              __builtin_amdgcn_mfma_f32_16x16x32_bf16(af, pb[k], accO[dt], 0, 0, 0);
        }
      }
    }
    __syncthreads();
    cur ^= 1;
  }
#undef STAGE

  ssum += __shfl_xor(ssum, 16);
  ssum += __shfl_xor(ssum, 32);
  float inv = 1.f / ssum;
  short* rowO = r2 + (size_t)n * 256;
#pragma unroll
  for (int dt = 0; dt < 8; ++dt) {
    short4 o;
    o.x = f2bf(accO[dt][0] * inv);
    o.y = f2bf(accO[dt][1] * inv);
    o.z = f2bf(accO[dt][2] * inv);
    o.w = f2bf(accO[dt][3] * inv);
    *(short4*)&rowO[(dt >> 1) * 32 + lg * 8 + (dt & 1) * 4] = o;
  }
}

// ---------------------------------------------------------------------------
// Kernel 4: MFMA GEMM2 (bf16, K=512 concat, packed operands) + bias +
//   transposed store (unchanged).
// ---------------------------------------------------------------------------
__global__ __launch_bounds__(512) void gemm2_mfma(
    const short* __restrict__ r2s, const short* __restrict__ r2t,
    const short* __restrict__ W2b,  // [336][512] bf16 packed
    const float* __restrict__ b2,   // [336]
    float* __restrict__ out) {
  __shared__ __align__(16) short w2lds[2][112 * 40];  // 17.9 KB
  int tid = threadIdx.x;
  int w = tid >> 6, l = tid & 63, lr = l & 15, lg = l >> 4;
  int p0 = blockIdx.y * 112;
  int n = blockIdx.x * 128 + w * 16 + lr;
  int b = n / CC, c = n - b * CC;
  const short* rs = r2s + (size_t)n * 256;
  const short* rt = r2t + (size_t)n * 256;

  bool dostage = tid < 448;
  int row = tid >> 2, q = tid & 3;
  const short* gW = W2b + (size_t)(p0 + row) * 512 + q * 8;
  int doff = row * 40 + q * 8;

  f32x4 acc[7];
#pragma unroll
  for (int i = 0; i < 7; ++i) acc[i] = (f32x4){0.f, 0.f, 0.f, 0.f};

  if (dostage) *(int4*)&w2lds[0][doff] = *(const int4*)gW;
  __syncthreads();

  int cur = 0;
  for (int step = 0; step < 16; ++step) {
    int k0 = step * 32;
    const short* rrow = ((k0 < 256) ? rs : rt) + (k0 & 255);
    bf16x8 bfr = *(const bf16x8*)&rrow[lg * 8];
    int4 nxt = {0, 0, 0, 0};
    if (step < 15 && dostage) nxt = *(const int4*)(gW + (step + 1) * 32);
    const short* tw = &w2lds[cur][0];
#pragma unroll
    for (int pt = 0; pt < 7; ++pt) {
      bf16x8 a = *(const bf16x8*)&tw[(pt * 16 + lr) * 40 + lg * 8];
      acc[pt] = __builtin_amdgcn_mfma_f32_16x16x32_bf16(a, bfr, acc[pt], 0, 0, 0);
    }
    if (step < 15 && dostage) *(int4*)&w2lds[cur ^ 1][doff] = nxt;
    __syncthreads();
    cur ^= 1;
  }

  size_t obase = (size_t)b * ((size_t)PP * CC) + c;
#pragma unroll
  for (int pt = 0; pt < 7; ++pt) {
    int p = p0 + pt * 16 + lg * 4;
    float4 bias = *(const float4*)&b2[p];
    const float* pb = &bias.x;
#pragma unroll
    for (int j = 0; j < 4; ++j) {
      out[obase + (size_t)(p + j) * CC] = acc[pt][j] + pb[j];
    }
  }
}

// ---------------------------------------------------------------------------
extern "C" void kernel_launch(void* const* d_in, const int* in_sizes, int n_in,
                              void* d_out, int out_size, void* d_ws, size_t ws_size,
                              hipStream_t stream) {
  const float* x    = (const float*)d_in[0];
  const float* Ws1  = (const float*)d_in[1];
  const float* bs1  = (const float*)d_in[2];
  const float* Ws2  = (const float*)d_in[3];
  const float* bs2  = (const float*)d_in[4];
  const float* Wt1  = (const float*)d_in[5];
  const float* bt1  = (const float*)d_in[6];
  const float* Wt2  = (const float*)d_in[7];
  const float* bt2  = (const float*)d_in[8];
  const float* memS = (const float*)d_in[9];
  const float* memT = (const float*)d_in[10];
  float* out = (float*)d_out;

  const size_t N = (size_t)BB * CC;          // 41088
  short* r2s  = (short*)d_ws;                // [N][256] bf16 packed: [O | R]
  short* r2t  = r2s + N * 256;
  short* wimg = r2t + N * 256;               // [23][128][128B] = 368 KB
  short* stgS = wimg + (size_t)NSTEP * 128 * 64;
  short* stgT = stgS + (size_t)16384 * 8;
  short* W2b  = stgT + (size_t)16384 * 8;    // [336][512] bf16 packed
  float* b2   = (float*)(W2b + (size_t)PP * 512);
  short* ximg = (short*)(b2 + PP);           // [642][23][2048] = 60.5 MB

  // 1. precompute weights / staged conversions
  weff_kernel<<<(HH * NSTEP * 32 + 255) / 256, 256, 0, stream>>>(Ws1, Wt1, wimg);
  memstage_kernel<<<128, 256, 0, stream>>>(memS, memT, stgS, stgT);
  w2cvt_kernel<<<(PP * 512) / 256, 256, 0, stream>>>(Ws2, Wt2, bs2, bt2, W2b, b2);

  // 1d. x -> staged bf16 images (dense coalesced writes)
  dim3 gx(642, NSTEP);
  xstage_kernel<<<gx, 64, 0, stream>>>(x, ximg);

  // 2. MFMA GEMM1 + sigmoid (both branches), pure-gload_lds, grid 642
  gemm1_mfma<<<642, 256, 0, stream>>>(wimg, ximg, bs1, bt1, r2s, r2t);

  // 3. pipelined MFMA memory enhance, both branches in one dispatch
  dim3 g3(642, 2);
  memenh_mfma<<<g3, 256, 0, stream>>>(stgS, stgT, r2s, r2t);

  // 4. MFMA GEMM2 + bias + transposed store
  dim3 g2(321, 3);
  gemm2_mfma<<<g2, 512, 0, stream>>>(r2s, r2t, W2b, b2, out);
}

// Round 17
// 151.131 us; speedup vs baseline: 1.0521x; 1.0521x over previous
//
#include <hip/hip_runtime.h>
#include <math.h>

#define BB 128
#define LL 720
#define CC 321
#define HH 128
#define PP 336
#define MM 512
#define NSTEP 23   // K-steps of 32 (736 = 23*32, zero-padded past 720)

typedef __attribute__((ext_vector_type(8))) short bf16x8;
typedef __attribute__((ext_vector_type(4))) float f32x4;

__device__ __forceinline__ short f2bf(float x) {
  unsigned u = __builtin_bit_cast(unsigned, x);
  u = (u + 0x7FFFu + ((u >> 16) & 1u)) >> 16;
  return (short)u;
}

// packed position of k-within-32-group: fragment lg*8 + half*4 + j
__device__ __forceinline__ int packpos(int kw) {
  return ((kw & 15) >> 2) * 8 + (kw >> 4) * 4 + (kw & 3);
}

// async global->LDS, 16 bytes per lane; lds ptr must be wave-uniform base
__device__ __forceinline__ void gload_lds16(const short* g, short* l) {
  __builtin_amdgcn_global_load_lds(
      (const __attribute__((address_space(1))) unsigned int*)g,
      (__attribute__((address_space(3))) unsigned int*)l, 16, 0, 0);
}

// ---------------------------------------------------------------------------
// Kernel 1 (v5): smeared weights -> W image for gemm1 (BK=32). Unchanged:
//   wimg[s][h] = 64-short row of 8 16B slots; slot (br*4+lg)^(h&7) holds the
//   packed fragment of Weff_br[h][s*32 + ...]. 23 x 16 KB = 368 KB.
// ---------------------------------------------------------------------------
__global__ void weff_kernel(const float* __restrict__ Ws1,
                            const float* __restrict__ Wt1,
                            short* __restrict__ wimg) {
  int idx = blockIdx.x * 256 + threadIdx.x;
  if (idx >= HH * NSTEP * 32) return;
  int j = idx % (NSTEP * 32), h = idx / (NSTEP * 32);
  int s = j >> 5, kw = j & 31;
  int half = kw >> 4, lg = (kw >> 2) & 3, jj = kw & 3;
  size_t base = ((size_t)(s * 128 + h)) * 64 + half * 4 + jj;
  int slotS = (0 + lg) ^ (h & 7);
  int slotT = (4 + lg) ^ (h & 7);
  if (j >= LL) {
    wimg[base + slotS * 8] = 0;
    wimg[base + slotT * 8] = 0;
    return;
  }
  float ss = 0.f, st = 0.f;
  if (j == 0) {
    for (int l = 0; l <= 12; ++l) {
      float w = 13.f - (float)l;
      ss += w * Ws1[h * LL + l];
      st += w * Wt1[h * LL + l];
    }
  } else if (j == LL - 1) {
    for (int d = 0; d <= 12; ++d) {
      float w = 13.f - (float)d;
      ss += w * Ws1[h * LL + LL - 1 - d];
      st += w * Wt1[h * LL + LL - 1 - d];
    }
  } else {
    int lo = j - 12 < 0 ? 0 : j - 12;
    int hi = j + 12 > LL - 1 ? LL - 1 : j + 12;
    for (int l = lo; l <= hi; ++l) {
      ss += Ws1[h * LL + l];
      st += Wt1[h * LL + l];
    }
  }
  ss *= (1.f / 25.f);
  st *= (1.f / 25.f);
  wimg[base + slotS * 8] = f2bf(Ws1[h * LL + j] - ss);
  wimg[base + slotT * 8] = f2bf(st);
}

// ---------------------------------------------------------------------------
// Kernel 1b: staged mem images for memenh (unchanged).
// ---------------------------------------------------------------------------
__global__ void memstage_kernel(const float* __restrict__ memS,
                                const float* __restrict__ memT,
                                short* __restrict__ stgS,
                                short* __restrict__ stgT) {
  int e = blockIdx.x * 256 + threadIdx.x;  // 0..32767
  int br = e >> 14;
  int s = e & 16383;
  const float* src = br ? memT : memS;
  short* dst = br ? stgT : stgS;
  int tt = s >> 11;                        // tile 0..7
  int c = s & 2047;
  int row = c >> 4, slot = c & 15;
  int sp = slot ^ (row & 7);
  int k = sp >> 2, lg = sp & 3;
  int ft = tt >> 1;
  short out[8];
  if ((tt & 1) == 0) {
    const float* r0 = src + (size_t)(ft * 128 + row) * 128 + k * 32 + lg * 4;
#pragma unroll
    for (int j = 0; j < 4; ++j) {
      out[j] = f2bf(r0[j]);
      out[j + 4] = f2bf(r0[16 + j]);
    }
  } else {
    int fbase = ft * 128 + k * 32 + lg * 4;
#pragma unroll
    for (int j = 0; j < 4; ++j) {
      out[j] = f2bf(src[(size_t)(fbase + j) * 128 + row]);
      out[j + 4] = f2bf(src[(size_t)(fbase + 16 + j) * 128 + row]);
    }
  }
  short4 a = make_short4(out[0], out[1], out[2], out[3]);
  short4 b = make_short4(out[4], out[5], out[6], out[7]);
  *(short4*)&dst[(size_t)s * 8] = a;
  *(short4*)&dst[(size_t)s * 8 + 4] = b;
}

// ---------------------------------------------------------------------------
// Kernel 1c: W2cat bf16 [336][512], fragment-packed per 32-group, + bias sum.
// ---------------------------------------------------------------------------
__global__ void w2cvt_kernel(const float* __restrict__ Ws2,
                             const float* __restrict__ Wt2,
                             const float* __restrict__ bs2,
                             const float* __restrict__ bt2,
                             short* __restrict__ W2b, float* __restrict__ b2) {
  int i = blockIdx.x * 256 + threadIdx.x;
  if (i < PP) b2[i] = bs2[i] + bt2[i];
  if (i >= PP * 512) return;
  int p = i >> 9, k = i & 511;
  float v = (k < 256) ? Ws2[p * 256 + k] : Wt2[p * 256 + (k - 256)];
  W2b[p * 512 + (k >> 5) * 32 + packpos(k & 31)] = f2bf(v);
}

// ---------------------------------------------------------------------------
// Kernel 2 (v12): MFMA dual-branch GEMM1 + sigmoid with FUSED x transpose.
//   Block = 64 n x 128 h x 2 br; 256 thr / 4 waves; BK=32, 23 steps; grid 642.
//   W: gload_lds from pre-swizzled wimg (unchanged, 4/thread/step).
//   x: per step, the 32k x 64n fp32 tile is read with float4 ROW loads
//      (1 KB dense per wave-instr — the r10-r16 1.4 TB/s wall was per-lane
//      dword gathers), converted to bf16, written via 2 b64 into a padded
//      transpose layout: idx = (nl&15) + (kk&3)*16 + ((kk>>2)&3)*72
//                            + (kk>>4)*288 + (nl>>4)*576
//      (72-short row stride -> fragment u16 reads are <=2-way bank = free).
//   Fragments: W 1 b128; x 8 u16 per fragment.
// ---------------------------------------------------------------------------
__global__ __launch_bounds__(256) void gemm1_mfma(
    const float* __restrict__ x, const short* __restrict__ wimg,
    const float* __restrict__ bs1, const float* __restrict__ bt1,
    short* __restrict__ r2s, short* __restrict__ r2t) {
  __shared__ __align__(16) short wbuf[2][8192];  // 2 x 16 KB
  __shared__ __align__(16) short xbuf[2][2304];  // 2 x 4.5 KB
  int tid = threadIdx.x;
  int w = tid >> 6, l = tid & 63, lr = l & 15, lg = l >> 4;
  int br = w >> 1, hb = (w & 1) * 64;
  int nb = blockIdx.x * 64;  // 41088 = 642*64 exact

  const short* wsrc = wimg + (size_t)w * 2048 + l * 8;

  // x chunk descriptors: chunks e = tid, tid+256; kk = e>>4, c4 = e&15
  const float* cbase[2];
  int coff[2][4];
  bool ccross[2];
  int ckk[2], cdst[2];
#pragma unroll
  for (int i = 0; i < 2; ++i) {
    int e = tid + i * 256;
    int kk = e >> 4, c4 = e & 15;
    ckk[i] = kk;
    int n0 = nb + c4 * 4;
    int b0 = n0 / CC, c0 = n0 - b0 * CC;
    cbase[i] = x + (size_t)b0 * (LL * CC) + c0;
    ccross[i] = (c0 + 3 >= CC);
#pragma unroll
    for (int j = 0; j < 4; ++j)
      coff[i][j] = j + ((c0 + j >= CC) ? (LL - 1) * CC : 0);
    cdst[i] = (c4 & 3) * 4 + (kk & 3) * 16 + ((kk >> 2) & 3) * 72 +
              (kk >> 4) * 288 + (c4 >> 2) * 576;
  }

#define XLOAD(i, s_, out)                                                  \
  do {                                                                     \
    int k_ = (s_)*32 + ckk[i];                                             \
    if (k_ < LL) {                                                         \
      if (!ccross[i]) {                                                    \
        float4 t4 = *(const float4*)(cbase[i] + (size_t)k_ * CC);          \
        out[0] = t4.x; out[1] = t4.y; out[2] = t4.z; out[3] = t4.w;        \
      } else {                                                             \
        _Pragma("unroll") for (int j = 0; j < 4; ++j)                      \
            out[j] = cbase[i][(size_t)k_ * CC + coff[i][j]];               \
      }                                                                    \
    } else {                                                               \
      out[0] = out[1] = out[2] = out[3] = 0.f;                             \
    }                                                                      \
  } while (0)

  f32x4 acc[4][4];  // [ht][ng]
#pragma unroll
  for (int i = 0; i < 4; ++i)
#pragma unroll
    for (int g = 0; g < 4; ++g) acc[i][g] = (f32x4){0.f, 0.f, 0.f, 0.f};

  // ---- prologue: stage step 0 ----
  {
    float xv0[4], xv1[4];
    XLOAD(0, 0, xv0);
    XLOAD(1, 0, xv1);
#pragma unroll
    for (int i = 0; i < 4; ++i)
      gload_lds16(wsrc + i * 512, &wbuf[0][w * 2048 + i * 512]);
    short4 s0 = make_short4(f2bf(xv0[0]), f2bf(xv0[1]), f2bf(xv0[2]),
                            f2bf(xv0[3]));
    short4 s1 = make_short4(f2bf(xv1[0]), f2bf(xv1[1]), f2bf(xv1[2]),
                            f2bf(xv1[3]));
    *(short4*)&xbuf[0][cdst[0]] = s0;
    *(short4*)&xbuf[0][cdst[1]] = s1;
  }
  __syncthreads();

  int cur = 0;
  for (int s = 0; s < NSTEP; ++s) {
    // prefetch next step: x float4 -> regs, W -> wbuf[cur^1]
    float xn0[4], xn1[4];
    if (s < NSTEP - 1) {
      XLOAD(0, s + 1, xn0);
      XLOAD(1, s + 1, xn1);
      const short* ws = wsrc + (size_t)(s + 1) * 8192;
#pragma unroll
      for (int i = 0; i < 4; ++i)
        gload_lds16(ws + i * 512, &wbuf[cur ^ 1][w * 2048 + i * 512]);
    }

    // compute current step
    const short* tw = &wbuf[cur][0];
    const short* tx = &xbuf[cur][0];
    bf16x8 afr[4], bfr[4];
#pragma unroll
    for (int ht = 0; ht < 4; ++ht) {
      int h = hb + ht * 16 + lr;
      int slot = (br * 4 + lg) ^ (h & 7);
      afr[ht] = *(const bf16x8*)&tw[h * 64 + slot * 8];
    }
#pragma unroll
    for (int ng = 0; ng < 4; ++ng) {
      int base0 = lr + lg * 72 + ng * 576;
      bf16x8 f;
#pragma unroll
      for (int j = 0; j < 4; ++j) {
        f[j] = tx[base0 + j * 16];
        f[j + 4] = tx[base0 + j * 16 + 288];
      }
      bfr[ng] = f;
    }
#pragma unroll
    for (int ht = 0; ht < 4; ++ht)
#pragma unroll
      for (int ng = 0; ng < 4; ++ng)
        acc[ht][ng] = __builtin_amdgcn_mfma_f32_16x16x32_bf16(
            afr[ht], bfr[ng], acc[ht][ng], 0, 0, 0);

    // commit next x tile (waits only on its own float4 loads)
    if (s < NSTEP - 1) {
      short4 s0 = make_short4(f2bf(xn0[0]), f2bf(xn0[1]), f2bf(xn0[2]),
                              f2bf(xn0[3]));
      short4 s1 = make_short4(f2bf(xn1[0]), f2bf(xn1[1]), f2bf(xn1[2]),
                              f2bf(xn1[3]));
      *(short4*)&xbuf[cur ^ 1][cdst[0]] = s0;
      *(short4*)&xbuf[cur ^ 1][cdst[1]] = s1;
    }
    __syncthreads();
    cur ^= 1;
  }
#undef XLOAD

  // epilogue: sigmoid -> PACKED bf16 R at shorts [128..255] of each r2 row
  const float* bias = br ? bt1 : bs1;
  short* r2 = br ? r2t : r2s;
#pragma unroll
  for (int ht = 0; ht < 4; ++ht) {
    int h0 = hb + ht * 16 + lg * 4;
    int dst = (h0 >> 5) * 32 + lg * 8 + ((h0 >> 4) & 1) * 4;
    float4 bi4 = *(const float4*)&bias[h0];
    const float* pb = &bi4.x;
#pragma unroll
    for (int ng = 0; ng < 4; ++ng) {
      int n = nb + ng * 16 + lr;
      short4 v;
      short* pv = &v.x;
#pragma unroll
      for (int j = 0; j < 4; ++j)
        pv[j] = f2bf(1.f / (1.f + __expf(-(acc[ht][ng][j] + pb[j]))));
      *(short4*)&r2[(size_t)n * 256 + 128 + dst] = v;
    }
  }
}

// ---------------------------------------------------------------------------
// Kernel 3: pipelined MFMA memory-enhance (unchanged).
// ---------------------------------------------------------------------------
__global__ __launch_bounds__(256) void memenh_mfma(
    const short* __restrict__ stgS, const short* __restrict__ stgT,
    short* __restrict__ r2s, short* __restrict__ r2t) {
  int br = blockIdx.y;
  const short* stg = br ? stgT : stgS;
  short* r2 = br ? r2t : r2s;

  __shared__ __align__(16) short buf[2][16384];  // 64 KB
  int tid = threadIdx.x;
  int l = tid & 63, lr = l & 15, lg = l >> 4;
  int wbase = tid & 192;
  int n = blockIdx.x * 64 + (tid >> 6) * 16 + lr;

  bf16x8 brag[4];
  {
    const short* rb = r2 + (size_t)n * 256 + 128;
#pragma unroll
    for (int k = 0; k < 4; ++k)
      brag[k] = *(const bf16x8*)&rb[k * 32 + lg * 8];
  }

#define STAGE(t, bsel)                                                        \
  {                                                                           \
    const short* g = stg + (size_t)(t)*16384;                                 \
    _Pragma("unroll") for (int i = 0; i < 8; ++i) {                           \
      gload_lds16(g + (size_t)(i * 256 + tid) * 8,                            \
                  &buf[bsel][(i * 256 + wbase) * 8]);                         \
    }                                                                         \
  }

  STAGE(0, 0);
  __syncthreads();

  f32x4 accO[8];
#pragma unroll
  for (int i = 0; i < 8; ++i) accO[i] = (f32x4){0.f, 0.f, 0.f, 0.f};
  bf16x8 pb[4];
  float ssum = 0.f;
  int cur = 0;

#pragma unroll
  for (int t = 0; t < 8; ++t) {
    if (t < 7) STAGE(t + 1, cur ^ 1);
    const short* tb = &buf[cur][0];
    if ((t & 1) == 0) {
      f32x4 sc[8];
#pragma unroll
      for (int ft16 = 0; ft16 < 8; ++ft16) {
        f32x4 a = {0.f, 0.f, 0.f, 0.f};
#pragma unroll
        for (int k = 0; k < 4; ++k) {
          int row = ft16 * 16 + lr;
          int slot = (4 * k + lg) ^ (row & 7);
          bf16x8 af = *(const bf16x8*)&tb[row * 128 + slot * 8];
          a = __builtin_amdgcn_mfma_f32_16x16x32_bf16(af, brag[k], a, 0, 0, 0);
        }
        sc[ft16] = a;
      }
#pragma unroll
      for (int i = 0; i < 8; ++i) {
        f32x4 v = sc[i];
#pragma unroll
        for (int j = 0; j < 4; ++j) {
          float e = __expf(v[j]);
          v[j] = e;
          ssum += e;
        }
        sc[i] = v;
      }
#pragma unroll
      for (int t4 = 0; t4 < 4; ++t4) {
        f32x4 e0 = sc[2 * t4], e1 = sc[2 * t4 + 1];
        bf16x8 f;
        f[0] = f2bf(e0[0]); f[1] = f2bf(e0[1]);
        f[2] = f2bf(e0[2]); f[3] = f2bf(e0[3]);
        f[4] = f2bf(e1[0]); f[5] = f2bf(e1[1]);
        f[6] = f2bf(e1[2]); f[7] = f2bf(e1[3]);
        pb[t4] = f;
      }
    } else {
#pragma unroll
      for (int dt = 0; dt < 8; ++dt) {
#pragma unroll
        for (int k = 0; k < 4; ++k) {
          int row = dt * 16 + lr;
          int slot = (4 * k + lg) ^ (row & 7);
          bf16x8 af = *(const bf16x8*)&tb[row * 128 + slot * 8];
          accO[dt] =
              __builtin_amdgcn_mfma_f32_16x16x32_bf16(af, pb[k], accO[dt], 0, 0, 0);
        }
      }
    }
    __syncthreads();
    cur ^= 1;
  }
#undef STAGE

  ssum += __shfl_xor(ssum, 16);
  ssum += __shfl_xor(ssum, 32);
  float inv = 1.f / ssum;
  short* rowO = r2 + (size_t)n * 256;
#pragma unroll
  for (int dt = 0; dt < 8; ++dt) {
    short4 o;
    o.x = f2bf(accO[dt][0] * inv);
    o.y = f2bf(accO[dt][1] * inv);
    o.z = f2bf(accO[dt][2] * inv);
    o.w = f2bf(accO[dt][3] * inv);
    *(short4*)&rowO[(dt >> 1) * 32 + lg * 8 + (dt & 1) * 4] = o;
  }
}

// ---------------------------------------------------------------------------
// Kernel 4: MFMA GEMM2 (bf16, K=512 concat, packed operands) + bias +
//   transposed store (unchanged).
// ---------------------------------------------------------------------------
__global__ __launch_bounds__(512) void gemm2_mfma(
    const short* __restrict__ r2s, const short* __restrict__ r2t,
    const short* __restrict__ W2b,  // [336][512] bf16 packed
    const float* __restrict__ b2,   // [336]
    float* __restrict__ out) {
  __shared__ __align__(16) short w2lds[2][112 * 40];  // 17.9 KB
  int tid = threadIdx.x;
  int w = tid >> 6, l = tid & 63, lr = l & 15, lg = l >> 4;
  int p0 = blockIdx.y * 112;
  int n = blockIdx.x * 128 + w * 16 + lr;
  int b = n / CC, c = n - b * CC;
  const short* rs = r2s + (size_t)n * 256;
  const short* rt = r2t + (size_t)n * 256;

  bool dostage = tid < 448;
  int row = tid >> 2, q = tid & 3;
  const short* gW = W2b + (size_t)(p0 + row) * 512 + q * 8;
  int doff = row * 40 + q * 8;

  f32x4 acc[7];
#pragma unroll
  for (int i = 0; i < 7; ++i) acc[i] = (f32x4){0.f, 0.f, 0.f, 0.f};

  if (dostage) *(int4*)&w2lds[0][doff] = *(const int4*)gW;
  __syncthreads();

  int cur = 0;
  for (int step = 0; step < 16; ++step) {
    int k0 = step * 32;
    const short* rrow = ((k0 < 256) ? rs : rt) + (k0 & 255);
    bf16x8 bfr = *(const bf16x8*)&rrow[lg * 8];
    int4 nxt = {0, 0, 0, 0};
    if (step < 15 && dostage) nxt = *(const int4*)(gW + (step + 1) * 32);
    const short* tw = &w2lds[cur][0];
#pragma unroll
    for (int pt = 0; pt < 7; ++pt) {
      bf16x8 a = *(const bf16x8*)&tw[(pt * 16 + lr) * 40 + lg * 8];
      acc[pt] = __builtin_amdgcn_mfma_f32_16x16x32_bf16(a, bfr, acc[pt], 0, 0, 0);
    }
    if (step < 15 && dostage) *(int4*)&w2lds[cur ^ 1][doff] = nxt;
    __syncthreads();
    cur ^= 1;
  }

  size_t obase = (size_t)b * ((size_t)PP * CC) + c;
#pragma unroll
  for (int pt = 0; pt < 7; ++pt) {
    int p = p0 + pt * 16 + lg * 4;
    float4 bias = *(const float4*)&b2[p];
    const float* pb = &bias.x;
#pragma unroll
    for (int j = 0; j < 4; ++j) {
      out[obase + (size_t)(p + j) * CC] = acc[pt][j] + pb[j];
    }
  }
}

// ---------------------------------------------------------------------------
extern "C" void kernel_launch(void* const* d_in, const int* in_sizes, int n_in,
                              void* d_out, int out_size, void* d_ws, size_t ws_size,
                              hipStream_t stream) {
  const float* x    = (const float*)d_in[0];
  const float* Ws1  = (const float*)d_in[1];
  const float* bs1  = (const float*)d_in[2];
  const float* Ws2  = (const float*)d_in[3];
  const float* bs2  = (const float*)d_in[4];
  const float* Wt1  = (const float*)d_in[5];
  const float* bt1  = (const float*)d_in[6];
  const float* Wt2  = (const float*)d_in[7];
  const float* bt2  = (const float*)d_in[8];
  const float* memS = (const float*)d_in[9];
  const float* memT = (const float*)d_in[10];
  float* out = (float*)d_out;

  const size_t N = (size_t)BB * CC;          // 41088
  short* r2s  = (short*)d_ws;                // [N][256] bf16 packed: [O | R]
  short* r2t  = r2s + N * 256;
  short* wimg = r2t + N * 256;               // [23][128][128B] = 368 KB
  short* stgS = wimg + (size_t)NSTEP * 128 * 64;
  short* stgT = stgS + (size_t)16384 * 8;
  short* W2b  = stgT + (size_t)16384 * 8;    // [336][512] bf16 packed
  float* b2   = (float*)(W2b + (size_t)PP * 512);
  // total ~= 46 MB (ximg removed)

  // 1. precompute weights / staged conversions
  weff_kernel<<<(HH * NSTEP * 32 + 255) / 256, 256, 0, stream>>>(Ws1, Wt1, wimg);
  memstage_kernel<<<128, 256, 0, stream>>>(memS, memT, stgS, stgT);
  w2cvt_kernel<<<(PP * 512) / 256, 256, 0, stream>>>(Ws2, Wt2, bs2, bt2, W2b, b2);

  // 2. MFMA GEMM1 + sigmoid (both branches), fused x transpose, grid 642
  gemm1_mfma<<<642, 256, 0, stream>>>(x, wimg, bs1, bt1, r2s, r2t);

  // 3. pipelined MFMA memory enhance, both branches in one dispatch
  dim3 g3(642, 2);
  memenh_mfma<<<g3, 256, 0, stream>>>(stgS, stgT, r2s, r2t);

  // 4. MFMA GEMM2 + bias + transposed store
  dim3 g2(321, 3);
  gemm2_mfma<<<g2, 512, 0, stream>>>(r2s, r2t, W2b, b2, out);
}